// Round 1
// baseline (1025.619 us; speedup 1.0000x reference)
//
#include <hip/hip_runtime.h>
#include <hip/hip_bf16.h>

// Qwen3 MoE expert FFN: out = (silu(x@Wg) * (x@Wu)) @ Wd, grouped by expert.
// E=64 experts, H=2048 hidden, I=768 inter, 64 tokens/expert (equal groups,
// as produced by setup_inputs and assumed by the reference's reshape).
//
// Strategy: HBM-bound on the 1.21 GB fp32 weight stream (~192 us floor at
// 6.3 TB/s). bf16 MFMA (16x16x32) with fp32 accumulate; weights staged
// coalesced fp32 -> bf16 -> LDS transposed [n][k] so B-frags are one
// ds_read_b128; A-frags read directly from global (K-contiguous, L2/L3 hot).

#define NE    64
#define HID   2048
#define ITR   768
#define GT    64    // tokens per expert

using short8  = __attribute__((ext_vector_type(8))) short;
using short4v = __attribute__((ext_vector_type(4))) short;
using f32x4   = __attribute__((ext_vector_type(4))) float;

__device__ __forceinline__ short f2bf(float f) {
  return __builtin_bit_cast(short, __float2bfloat16(f));  // RNE
}

// ---------------------------------------------------------------------------
// Kernel 1: h[t][n] = silu(x@Wg) * (x@Wu), h stored bf16 in workspace.
// Grid: 64 experts * 12 n-tiles (of 64) = 768 blocks, 256 threads (4 waves).
// Each wave: 16 rows x 64 cols, 4+4 f32x4 accumulators (gate, up).
// ---------------------------------------------------------------------------
__global__ __launch_bounds__(256, 3) void ffn_gateup(
    const float* __restrict__ x,
    const float* __restrict__ Wg,
    const float* __restrict__ Wu,
    __hip_bfloat16* __restrict__ hbuf)
{
  constexpr int SK = 72;                 // LDS k-stride (bf16): 144 B, 16B-aligned rows
  __shared__ short sb[2][GT * SK];       // [matrix][n=64][k=64] transposed tiles

  const int t  = threadIdx.x;
  const int w  = t >> 6;                 // wave 0..3 -> m-slice
  const int l  = t & 63;
  const int r  = l & 15;                 // MFMA: A-row / B-col / C-col
  const int g  = l >> 4;                 // MFMA quad: k-group / C-row-group
  const int e  = blockIdx.x / 12;
  const int nt = blockIdx.x % 12;
  const int n0 = nt * 64;

  const int skp = t >> 4;                // staging: k-patch 0..15 (4 rows each)
  const int snp = t & 15;                // staging: n-patch (4 cols each)

  const float* xrow = x + (size_t)(e * GT + 16 * w + r) * HID;
  const float* wgb  = Wg + (size_t)e * HID * ITR + n0 + 4 * snp;
  const float* wub  = Wu + (size_t)e * HID * ITR + n0 + 4 * snp;

  f32x4 accg[4] = {};
  f32x4 accu[4] = {};

  for (int k0 = 0; k0 < HID; k0 += 64) {
    __syncthreads();   // previous tile fully consumed
    {
      // coalesced fp32 reads: 16 lanes x float4 = 256 B contiguous per k-row
      const float* sg = wgb + (size_t)(k0 + 4 * skp) * ITR;
      const float* su = wub + (size_t)(k0 + 4 * skp) * ITR;
      f32x4 g0 = *(const f32x4*)(sg);
      f32x4 g1 = *(const f32x4*)(sg + ITR);
      f32x4 g2 = *(const f32x4*)(sg + 2 * ITR);
      f32x4 g3 = *(const f32x4*)(sg + 3 * ITR);
      f32x4 u0 = *(const f32x4*)(su);
      f32x4 u1 = *(const f32x4*)(su + ITR);
      f32x4 u2 = *(const f32x4*)(su + 2 * ITR);
      f32x4 u3 = *(const f32x4*)(su + 3 * ITR);
      short* d0 = &sb[0][(4 * snp) * SK + 4 * skp];
      short* d1 = &sb[1][(4 * snp) * SK + 4 * skp];
#pragma unroll
      for (int i = 0; i < 4; ++i) {      // transpose 4x4 patch, b64 LDS writes
        short4v pg = { f2bf(g0[i]), f2bf(g1[i]), f2bf(g2[i]), f2bf(g3[i]) };
        short4v pu = { f2bf(u0[i]), f2bf(u1[i]), f2bf(u2[i]), f2bf(u3[i]) };
        *(short4v*)(d0 + i * SK) = pg;
        *(short4v*)(d1 + i * SK) = pu;
      }
    }
    __syncthreads();

#pragma unroll
    for (int kk = 0; kk < 64; kk += 32) {
      const int kb = kk + 8 * g;
      // A-frag direct from global: 8 consecutive fp32 -> bf16x8
      const float* ap = xrow + k0 + kb;
      f32x4 a0 = *(const f32x4*)ap;
      f32x4 a1 = *(const f32x4*)(ap + 4);
      short8 af = { f2bf(a0[0]), f2bf(a0[1]), f2bf(a0[2]), f2bf(a0[3]),
                    f2bf(a1[0]), f2bf(a1[1]), f2bf(a1[2]), f2bf(a1[3]) };
#pragma unroll
      for (int c = 0; c < 4; ++c) {
        short8 bg = *(const short8*)&sb[0][(16 * c + r) * SK + kb];
        short8 bu = *(const short8*)&sb[1][(16 * c + r) * SK + kb];
        accg[c] = __builtin_amdgcn_mfma_f32_16x16x32_bf16(af, bg, accg[c], 0, 0, 0);
        accu[c] = __builtin_amdgcn_mfma_f32_16x16x32_bf16(af, bu, accu[c], 0, 0, 0);
      }
    }
  }

  // epilogue: SwiGLU, write bf16 h. C/D layout: col = lane&15, row = 4*(lane>>4)+i
  __hip_bfloat16* hb = hbuf + (size_t)(e * GT + 16 * w + 4 * g) * ITR + n0 + r;
#pragma unroll
  for (int c = 0; c < 4; ++c) {
#pragma unroll
    for (int i = 0; i < 4; ++i) {
      float gv = accg[c][i];
      float uv = accu[c][i];
      float hv = gv / (1.f + __expf(-gv)) * uv;
      hb[i * ITR + 16 * c] = __float2bfloat16(hv);
    }
  }
}

// ---------------------------------------------------------------------------
// Kernel 2: out[t][n] = h @ Wd (per expert). Grid: 64 * 32 n-tiles = 2048.
// ---------------------------------------------------------------------------
__global__ __launch_bounds__(256, 4) void ffn_down(
    const __hip_bfloat16* __restrict__ hbuf,
    const float* __restrict__ Wd,
    float* __restrict__ out)
{
  constexpr int SK = 72;
  __shared__ short sb[GT * SK];

  const int t  = threadIdx.x;
  const int w  = t >> 6;
  const int l  = t & 63;
  const int r  = l & 15;
  const int g  = l >> 4;
  const int e  = blockIdx.x >> 5;
  const int nt = blockIdx.x & 31;
  const int n0 = nt * 64;

  const int skp = t >> 4;
  const int snp = t & 15;

  const __hip_bfloat16* hrow = hbuf + (size_t)(e * GT + 16 * w + r) * ITR;
  const float* wdb = Wd + (size_t)e * ITR * HID + n0 + 4 * snp;

  f32x4 acc[4] = {};

  for (int k0 = 0; k0 < ITR; k0 += 64) {
    __syncthreads();
    {
      const float* s = wdb + (size_t)(k0 + 4 * skp) * HID;
      f32x4 v0 = *(const f32x4*)(s);
      f32x4 v1 = *(const f32x4*)(s + HID);
      f32x4 v2 = *(const f32x4*)(s + 2 * HID);
      f32x4 v3 = *(const f32x4*)(s + 3 * HID);
      short* d = &sb[(4 * snp) * SK + 4 * skp];
#pragma unroll
      for (int i = 0; i < 4; ++i) {
        short4v p = { f2bf(v0[i]), f2bf(v1[i]), f2bf(v2[i]), f2bf(v3[i]) };
        *(short4v*)(d + i * SK) = p;
      }
    }
    __syncthreads();

#pragma unroll
    for (int kk = 0; kk < 64; kk += 32) {
      const int kb = kk + 8 * g;
      short8 af = *(const short8*)(hrow + k0 + kb);   // h already bf16
#pragma unroll
      for (int c = 0; c < 4; ++c) {
        short8 bf = *(const short8*)&sb[(16 * c + r) * SK + kb];
        acc[c] = __builtin_amdgcn_mfma_f32_16x16x32_bf16(af, bf, acc[c], 0, 0, 0);
      }
    }
  }

  float* ob = out + (size_t)(e * GT + 16 * w + 4 * g) * HID + n0 + r;
#pragma unroll
  for (int c = 0; c < 4; ++c) {
#pragma unroll
    for (int i = 0; i < 4; ++i) {
      ob[i * HID + 16 * c] = acc[c][i];
    }
  }
}

// ---------------------------------------------------------------------------
extern "C" void kernel_launch(void* const* d_in, const int* in_sizes, int n_in,
                              void* d_out, int out_size, void* d_ws, size_t ws_size,
                              hipStream_t stream) {
  const float* x  = (const float*)d_in[0];
  // d_in[1] = grouped_mm_offs (int64) — equal groups of 64 by construction
  const float* Wg = (const float*)d_in[2];
  const float* Wu = (const float*)d_in[3];
  const float* Wd = (const float*)d_in[4];
  float* out = (float*)d_out;
  __hip_bfloat16* hbuf = (__hip_bfloat16*)d_ws;  // 4096*768 bf16 = 6.3 MB

  hipLaunchKernelGGL(ffn_gateup, dim3(NE * (ITR / 64)), dim3(256), 0, stream,
                     x, Wg, Wu, hbuf);
  hipLaunchKernelGGL(ffn_down, dim3(NE * (HID / 64)), dim3(256), 0, stream,
                     hbuf, Wd, out);
}